// Round 11
// baseline (100.863 us; speedup 1.0000x reference)
//
#include <hip/hip_runtime.h>

// SNN-FiLM v11 — single-variable A/B vs v6/v10: block granularity
// 2048×(8 slices/wave) -> 4096×(4 slices/wave). Trend: 1024 blocks=102.4,
// 2048 blocks=97.8/98.1; testing 4096. Everything else identical (nt both
// ways, 2-ahead pipeline, scalar gamma/beta, launch_bounds(256,4)).
//   x:        [T=16, B=16, C=256, H=32, W=32]  f32  (256 MB)
//   condition:[T=16, B=16, Cc=256]             f32
//   W:        [2C=512, Cc=256]                 f32
//   b:        [512]                            f32
//   out = (gamma+1)*x + beta

#define T_STEPS 16
#define B_SZ    16
#define C_SZ    256
#define CC_SZ   256
#define HW      1024
#define THREADS 256
#define WS      4            // slices per wave

typedef float f4 __attribute__((ext_vector_type(4)));

__device__ __forceinline__ float qreduce(float v) {   // sum over 4-lane group
    v += __shfl_xor(v, 1);
    v += __shfl_xor(v, 2);
    return v;
}

// ---------------------------------------------------------------------------
// Kernel A — params (unchanged): params[t*16+b][d]; gamma rows stored with
// +1+bias baked in, beta rows with +bias. 512 blocks.
// ---------------------------------------------------------------------------
__global__ __launch_bounds__(THREADS)
void params_kernel(const float* __restrict__ cond,
                   const float* __restrict__ W,
                   const float* __restrict__ bias,
                   float* __restrict__ params)
{
    __shared__ f4 s_spk[CC_SZ];        // [cc] -> spikes for t = tg*4 .. tg*4+3

    const int bid = blockIdx.x;        // 0..511
    const int tg  = bid & 3;           // t-group (4 t's)
    const int dg  = (bid >> 2) & 7;    // d-group (64 rows)
    const int b   = bid >> 5;          // batch
    const int tid = threadIdx.x;

    // ---- LIF: one full 16-step chain per cc, record this block's 4 t's ----
    {
        const float* cp = cond + (size_t)b * CC_SZ + tid;
        float v = 0.0f;
        f4 rec = {0.f, 0.f, 0.f, 0.f};
#pragma unroll
        for (int t = 0; t < T_STEPS; ++t) {
            float xv = cp[(size_t)t * (B_SZ * CC_SZ)];
            v = v + (xv - v) * 0.5f;                  // charge (TAU=2)
            float s = (v >= 1.0f) ? 1.0f : 0.0f;      // fire
            v = (s != 0.0f) ? 0.0f : v;               // hard reset
            const bool mine = ((t >> 2) == tg);       // runtime pred, static dst
            if ((t & 3) == 0) rec.x = mine ? s : rec.x;
            if ((t & 3) == 1) rec.y = mine ? s : rec.y;
            if ((t & 3) == 2) rec.z = mine ? s : rec.z;
            if ((t & 3) == 3) rec.w = mine ? s : rec.w;
        }
        s_spk[tid] = rec;
    }
    __syncthreads();

    // ---- dots: row r = tid>>2 (64 rows), K-quarter q = tid&3, 4 t's --------
    {
        const int r = tid >> 2;
        const int q = tid & 3;
        const int d = dg * 64 + r;                    // 0..511
        const f4* Wr = reinterpret_cast<const f4*>(W + (size_t)d * CC_SZ)
                       + q * 16;
        const f4* sp = s_spk + q * 64;
        f4 acc = {0.f, 0.f, 0.f, 0.f};                // acc[j] for t = tg*4+j
#pragma unroll
        for (int k = 0; k < 16; ++k) {
            f4 w  = Wr[k];
            f4 s0 = sp[4 * k + 0];
            f4 s1 = sp[4 * k + 1];
            f4 s2 = sp[4 * k + 2];
            f4 s3 = sp[4 * k + 3];
            acc += w.x * s0 + w.y * s1 + w.z * s2 + w.w * s3;
        }
        acc.x = qreduce(acc.x);
        acc.y = qreduce(acc.y);
        acc.z = qreduce(acc.z);
        acc.w = qreduce(acc.w);
        if (q == 0) {
            const float add = bias[d] + ((d < C_SZ) ? 1.0f : 0.0f); // bake +1
            float vals[4] = {acc.x + add, acc.y + add, acc.z + add, acc.w + add};
#pragma unroll
            for (int j = 0; j < 4; ++j) {
                const int t = tg * 4 + j;
                params[((size_t)t * B_SZ + b) * 512 + d] = vals[j];
            }
        }
    }
}

// ---------------------------------------------------------------------------
// Kernel B — pure streamer: 4096 blocks, 16 slices/block, 4 slices/wave,
// nt loads+stores, 2-ahead fully-unrolled pipeline, scalar gamma/beta.
// ---------------------------------------------------------------------------
__global__ __launch_bounds__(THREADS, 4)
void stream_kernel(const float* __restrict__ x,
                   const float* __restrict__ params,
                   float* __restrict__ out)
{
    const int bid  = blockIdx.x;           // 0..4095
    const int tb   = bid >> 4;             // t*16 + b   (16 blocks per tb)
    const int cb   = (bid & 15) * 16;      // block's c base (16 c's)
    const int tid  = threadIdx.x;
    const int wid  = __builtin_amdgcn_readfirstlane(tid >> 6);  // wave 0..3
    const int lane = tid & 63;

    const size_t base = ((size_t)tb * C_SZ + cb + wid * WS) * HW;
    const f4* __restrict__ xw = reinterpret_cast<const f4*>(x + base);
    f4*       __restrict__ ow = reinterpret_cast<f4*>(out + base);

    // ---- prefetch slices 0..1 (8 nt loads in flight) -----------------------
    f4 buf[WS][4];
#pragma unroll
    for (int s = 0; s < 2; ++s)
#pragma unroll
        for (int i = 0; i < 4; ++i)
            buf[s][i] = __builtin_nontemporal_load(
                &xw[(size_t)s * 256 + i * 64 + lane]);

    // ---- gamma/beta: wave-uniform addresses -> scalar loads ----------------
    const float* pg = params + (size_t)tb * 512 + cb + wid * WS;  // gamma+1
    const float* pb = pg + C_SZ;                                  // beta
    float g[WS], be[WS];
#pragma unroll
    for (int i = 0; i < WS; ++i) { g[i] = pg[i]; be[i] = pb[i]; }

    // ---- fully-unrolled 2-ahead pipeline (4 slices) ------------------------
#pragma unroll
    for (int s = 0; s < WS; ++s) {
        if (s + 2 < WS) {
#pragma unroll
            for (int i = 0; i < 4; ++i)
                buf[s + 2][i] = __builtin_nontemporal_load(
                    &xw[(size_t)(s + 2) * 256 + i * 64 + lane]);
        }
#pragma unroll
        for (int i = 0; i < 4; ++i) {
            f4 v = buf[s][i];
            f4 r;
            r.x = fmaf(g[s], v.x, be[s]);
            r.y = fmaf(g[s], v.y, be[s]);
            r.z = fmaf(g[s], v.z, be[s]);
            r.w = fmaf(g[s], v.w, be[s]);
            __builtin_nontemporal_store(r, &ow[(size_t)s * 256 + i * 64 + lane]);
        }
    }
}

// ---------------------------------------------------------------------------
extern "C" void kernel_launch(void* const* d_in, const int* in_sizes, int n_in,
                              void* d_out, int out_size, void* d_ws, size_t ws_size,
                              hipStream_t stream)
{
    const float* x    = (const float*)d_in[0];
    const float* cond = (const float*)d_in[1];
    const float* W    = (const float*)d_in[2];
    const float* bias = (const float*)d_in[3];
    float* out    = (float*)d_out;
    float* params = (float*)d_ws;              // 131072 f32 = 512 KB

    params_kernel<<<512, THREADS, 0, stream>>>(cond, W, bias, params);
    stream_kernel<<<4096, THREADS, 0, stream>>>(x, params, out);
}

// Round 12
// 97.691 us; speedup vs baseline: 1.0325x; 1.0325x over previous
//
#include <hip/hip_runtime.h>

// SNN-FiLM v12 (FINAL) — revert to the measured-best configuration
// (v6/v10: 97.8 / 98.1 µs). Two kernels: tiny param kernel + pure streamer.
//   x:        [T=16, B=16, C=256, H=32, W=32]  f32  (256 MB)
//   condition:[T=16, B=16, Cc=256]             f32
//   W:        [2C=512, Cc=256]                 f32
//   b:        [512]                            f32
//   out = (gamma+1)*x + beta
//
// A/B history (all measured, this session):
//   nt both ways beats cached by 12% (v7: 110.2 vs 97.8)
//   block sweep: 1024=102.4, 2048=97.8/98.1, 4096=100.9  -> 2048 optimal
//   pipeline depth 2 vs 3, occupancy 4 vs 8 blocks/CU: within noise
//   fused (single kernel) = 99.1; split wins
//   hipLaunchCooperativeKernel: unsupported in harness (silent no-launch)
// Stream runs ~5.8 TB/s = 92% of the 6.29 TB/s copy µbench ceiling.

#define T_STEPS 16
#define B_SZ    16
#define C_SZ    256
#define CC_SZ   256
#define HW      1024
#define THREADS 256

typedef float f4 __attribute__((ext_vector_type(4)));

__device__ __forceinline__ float qreduce(float v) {   // sum over 4-lane group
    v += __shfl_xor(v, 1);
    v += __shfl_xor(v, 2);
    return v;
}

// ---------------------------------------------------------------------------
// Kernel A — params: params[t*16+b][d]; gamma rows stored with +1+bias baked
// in, beta rows with +bias. Grid (b,dg,tg) = 16*8*4 = 512 blocks.
// ---------------------------------------------------------------------------
__global__ __launch_bounds__(THREADS)
void params_kernel(const float* __restrict__ cond,
                   const float* __restrict__ W,
                   const float* __restrict__ bias,
                   float* __restrict__ params)
{
    __shared__ f4 s_spk[CC_SZ];        // [cc] -> spikes for t = tg*4 .. tg*4+3

    const int bid = blockIdx.x;        // 0..511
    const int tg  = bid & 3;           // t-group (4 t's)
    const int dg  = (bid >> 2) & 7;    // d-group (64 rows)
    const int b   = bid >> 5;          // batch
    const int tid = threadIdx.x;

    // ---- LIF: one full 16-step chain per cc, record this block's 4 t's ----
    {
        const float* cp = cond + (size_t)b * CC_SZ + tid;
        float v = 0.0f;
        f4 rec = {0.f, 0.f, 0.f, 0.f};
#pragma unroll
        for (int t = 0; t < T_STEPS; ++t) {
            float xv = cp[(size_t)t * (B_SZ * CC_SZ)];
            v = v + (xv - v) * 0.5f;                  // charge (TAU=2)
            float s = (v >= 1.0f) ? 1.0f : 0.0f;      // fire
            v = (s != 0.0f) ? 0.0f : v;               // hard reset
            const bool mine = ((t >> 2) == tg);       // runtime pred, static dst
            if ((t & 3) == 0) rec.x = mine ? s : rec.x;
            if ((t & 3) == 1) rec.y = mine ? s : rec.y;
            if ((t & 3) == 2) rec.z = mine ? s : rec.z;
            if ((t & 3) == 3) rec.w = mine ? s : rec.w;
        }
        s_spk[tid] = rec;
    }
    __syncthreads();

    // ---- dots: row r = tid>>2 (64 rows), K-quarter q = tid&3, 4 t's --------
    {
        const int r = tid >> 2;
        const int q = tid & 3;
        const int d = dg * 64 + r;                    // 0..511
        const f4* Wr = reinterpret_cast<const f4*>(W + (size_t)d * CC_SZ)
                       + q * 16;
        const f4* sp = s_spk + q * 64;
        f4 acc = {0.f, 0.f, 0.f, 0.f};                // acc[j] for t = tg*4+j
#pragma unroll
        for (int k = 0; k < 16; ++k) {
            f4 w  = Wr[k];
            f4 s0 = sp[4 * k + 0];
            f4 s1 = sp[4 * k + 1];
            f4 s2 = sp[4 * k + 2];
            f4 s3 = sp[4 * k + 3];
            acc += w.x * s0 + w.y * s1 + w.z * s2 + w.w * s3;
        }
        acc.x = qreduce(acc.x);
        acc.y = qreduce(acc.y);
        acc.z = qreduce(acc.z);
        acc.w = qreduce(acc.w);
        if (q == 0) {
            const float add = bias[d] + ((d < C_SZ) ? 1.0f : 0.0f); // bake +1
            float vals[4] = {acc.x + add, acc.y + add, acc.z + add, acc.w + add};
#pragma unroll
            for (int j = 0; j < 4; ++j) {
                const int t = tg * 4 + j;
                params[((size_t)t * B_SZ + b) * 512 + d] = vals[j];
            }
        }
    }
}

// ---------------------------------------------------------------------------
// Kernel B — pure streamer: 2048 blocks, 32 slices/block, 8 slices/wave,
// nt loads+stores, 3-ahead fully-unrolled pipeline, scalar gamma/beta.
// ---------------------------------------------------------------------------
__global__ __launch_bounds__(THREADS, 4)
void stream_kernel(const float* __restrict__ x,
                   const float* __restrict__ params,
                   float* __restrict__ out)
{
    const int bid  = blockIdx.x;           // 0..2047
    const int tb   = bid >> 3;             // t*16 + b
    const int cb   = (bid & 7) * 32;       // block's c base
    const int tid  = threadIdx.x;
    const int wid  = __builtin_amdgcn_readfirstlane(tid >> 6);  // wave 0..3
    const int lane = tid & 63;

    const size_t base = ((size_t)tb * C_SZ + cb + wid * 8) * HW;
    const f4* __restrict__ xw = reinterpret_cast<const f4*>(x + base);
    f4*       __restrict__ ow = reinterpret_cast<f4*>(out + base);

    // ---- prefetch slices 0..2 (12 loads in flight before any dependency) --
    f4 buf[8][4];
#pragma unroll
    for (int s = 0; s < 3; ++s)
#pragma unroll
        for (int i = 0; i < 4; ++i)
            buf[s][i] = __builtin_nontemporal_load(
                &xw[(size_t)s * 256 + i * 64 + lane]);

    // ---- gamma/beta: wave-uniform addresses -> scalar loads ----------------
    const float* pg = params + (size_t)tb * 512 + cb + wid * 8;  // gamma+1
    const float* pb = pg + C_SZ;                                 // beta
    float g[8], be[8];
#pragma unroll
    for (int i = 0; i < 8; ++i) { g[i] = pg[i]; be[i] = pb[i]; }

    // ---- fully-unrolled 3-ahead pipeline -----------------------------------
#pragma unroll
    for (int s = 0; s < 8; ++s) {
        if (s + 3 < 8) {
#pragma unroll
            for (int i = 0; i < 4; ++i)
                buf[s + 3][i] = __builtin_nontemporal_load(
                    &xw[(size_t)(s + 3) * 256 + i * 64 + lane]);
        }
#pragma unroll
        for (int i = 0; i < 4; ++i) {
            f4 v = buf[s][i];
            f4 r;
            r.x = fmaf(g[s], v.x, be[s]);
            r.y = fmaf(g[s], v.y, be[s]);
            r.z = fmaf(g[s], v.z, be[s]);
            r.w = fmaf(g[s], v.w, be[s]);
            __builtin_nontemporal_store(r, &ow[(size_t)s * 256 + i * 64 + lane]);
        }
    }
}

// ---------------------------------------------------------------------------
extern "C" void kernel_launch(void* const* d_in, const int* in_sizes, int n_in,
                              void* d_out, int out_size, void* d_ws, size_t ws_size,
                              hipStream_t stream)
{
    const float* x    = (const float*)d_in[0];
    const float* cond = (const float*)d_in[1];
    const float* W    = (const float*)d_in[2];
    const float* bias = (const float*)d_in[3];
    float* out    = (float*)d_out;
    float* params = (float*)d_ws;              // 131072 f32 = 512 KB

    params_kernel<<<512, THREADS, 0, stream>>>(cond, W, bias, params);
    stream_kernel<<<2048, THREADS, 0, stream>>>(x, params, out);
}